// Round 7
// baseline (2738.095 us; speedup 1.0000x reference)
//
#include <hip/hip_runtime.h>
#include <cmath>

// Problem constants
#define B 32
#define T 512
#define D_IN 512
#define H 1024
#define NG 4096
#define L 4
#define D_OUT 512
#define RING 8

typedef _Float16 half8 __attribute__((ext_vector_type(8)));
typedef float    floatx4 __attribute__((ext_vector_type(4)));

// ---- workspace byte offsets ----
// Wpk: per (l,wg): [w][i 0..15][nt 0..3][lane 0..63][8 halves] = 256 KB -> 64 MB total
// Xt : [t][ktg 0..15][q][m 0..31][8 halves] fp16 tiled x     -> 16 MB
// Rt : [l][slot 0..7][ktg 0..31][q][m][8 halves] fp16 h ring -> 2 MB
// seq: int [L][64]  per-wg sequence numbers (seq = t+1 after h(t) published)
#define OFF_WPK 0ull
#define OFF_XT  67108864ull
#define OFF_RT  83886080ull
#define OFF_FLG 86114304ull

__device__ __forceinline__ int slot(int t) { return (t + 1) & (RING - 1); }
__device__ __forceinline__ float sigf(float x) { return 1.f / (1.f + __expf(-x)); }
__device__ __forceinline__ float tanhfast(float x) { return 2.f / (1.f + __expf(-2.f * x)) - 1.f; }

// Infinity-Cache-coherent data path (bypass L1/L2)
__device__ __forceinline__ void ld16(half8& d, const char* p) {
    asm volatile("global_load_dwordx4 %0, %1, off sc0 sc1" : "=v"(d) : "v"(p));
}
// plain cached load (L2-friendly) for constant tiles (Xt)
__device__ __forceinline__ void ld16nc(half8& d, const char* p) {
    asm volatile("global_load_dwordx4 %0, %1, off" : "=v"(d) : "v"(p));
}
__device__ __forceinline__ void st2(char* p, int v) {
    asm volatile("global_store_short %0, %1, off sc0 sc1" :: "v"(p), "v"(v));
}
__device__ __forceinline__ void ld4cv(int& d, const int* p) {
    asm volatile("global_load_dword %0, %1, off sc0 sc1" : "=v"(d) : "v"(p));
}
__device__ __forceinline__ void st4cv(int* p, int v) {
    asm volatile("global_store_dword %0, %1, off sc0 sc1" :: "v"(p), "v"(v));
}

// wave-parallel poll: lane i watches sp[0] (caller passes base+lane).
// Conservative fallback path for all gates.
__device__ __forceinline__ void poll64(const int* sp, int target) {
    int v;
    for (;;) {
        ld4cv(v, sp);
        asm volatile("s_waitcnt vmcnt(0)" : "+v"(v));
        if (__all(v >= target)) return;
        __builtin_amdgcn_s_sleep(2);
    }
}

// ---------------------------------------------------------------------------
// pack_w: fp32 weights -> fp16 B-fragments for mfma_f32_16x16x32_f16.
// B-frag layout: lane holds B[k = ktg*32 + (lane>>4)*8 + j][n = nt*1024 + wg*16 + (lane&15)]
// ktg = i*4 + w (K interleaved across waves). l=0: k in [512,1024) is zero pad.
// ---------------------------------------------------------------------------
__global__ __launch_bounds__(256) void pack_w(
    const float* __restrict__ Wx0, const float* __restrict__ Wh0,
    const float* __restrict__ Wx,  const float* __restrict__ Wh,
    uint32_t* __restrict__ dst)
{
    unsigned g = blockIdx.x * 256u + threadIdx.x;        // < 16,777,216
    unsigned lwg = g >> 16;
    int l = lwg >> 6, wg = lwg & 63;
    unsigned s = g & 65535u;
    int w  = s >> 14, i = (s >> 10) & 15, nt = (s >> 8) & 3;
    int q  = (s >> 6) & 3, jp = (s >> 4) & 3, r = s & 15;
    int k  = (i * 4 + w) * 32 + q * 8 + jp * 2;
    int n  = nt * 1024 + wg * 16 + r;

    float a, bv;
    if (l == 0) {
        if (k < 512)       { a = Wx0[(size_t)k * NG + n]; bv = Wx0[(size_t)(k + 1) * NG + n]; }
        else if (k < 1024) { a = 0.f; bv = 0.f; }
        else               { a = Wh0[(size_t)(k - 1024) * NG + n]; bv = Wh0[(size_t)(k - 1023) * NG + n]; }
    } else {
        const float* src;
        if (k < 1024) src = Wx + (size_t)(l - 1) * H * NG;
        else          src = Wh + (size_t)(l - 1) * H * NG - (size_t)1024 * NG;
        a  = src[(size_t)k * NG + n];
        bv = src[(size_t)(k + 1) * NG + n];
    }
    union { _Float16 h[2]; uint32_t u; } cv;
    cv.h[0] = (_Float16)a; cv.h[1] = (_Float16)bv;
    dst[(size_t)lwg * 65536 + (((size_t)(w * 16 + i) * 4 + nt) * 64 + q * 16 + r) * 4 + jp] = cv.u;
}

// ---------------------------------------------------------------------------
// tile_x: x fp32 [B][T][D_IN] -> Xt fp16 tiled [t][ktg][q][m][8]
// ---------------------------------------------------------------------------
__global__ __launch_bounds__(256) void tile_x(const float* __restrict__ x,
                                              uint32_t* __restrict__ dst)
{
    unsigned g = blockIdx.x * 256u + threadIdx.x;        // < 4,194,304
    int jp = g & 3, m = (g >> 2) & 31, q = (g >> 7) & 3, ktg = (g >> 9) & 15, t = g >> 13;
    int k = ktg * 32 + q * 8 + jp * 2;
    const float* xp = x + (size_t)m * (T * D_IN) + (size_t)t * D_IN + k;
    union { _Float16 h[2]; uint32_t u; } cv;
    cv.h[0] = (_Float16)xp[0]; cv.h[1] = (_Float16)xp[1];
    dst[g] = cv.u;
}

// ---------------------------------------------------------------------------
// Persistent MFMA LSTM. 256 blocks (4 layers x 64 wgs) x 256 threads.
// R7 = R6 (verified passing) + the SAME proven snapshot-ride pattern applied
// to the remaining two exposed condition waits:
//  * v3 (ring gate) now rides the PA load burst (was: issued just before
//    bar(c), full RT exposed at the update). Drained by PA/PB WAITV(0);
//    the update-site vmcnt(0) becomes free. 7-step slack vs ~1-2-step
//    upper-layer lag -> fast path hits.
//  * v2 (PA gate, l>0) now rides the PB load burst of the previous step
//    (was: issued at end of step, vmcnt(0)-waited at top of next step =
//    full RT). Top-of-step check is in-register; the vmcnt(1) there is a
//    compiler-ordering fence only (<=1 outstanding op = the fire-and-forget
//    flag store -> no actual wait; HW validity comes from PB's WAITV(0,3)
//    drain last step). Self-stabilizing: if the lower layer's lead is <2
//    the check misses -> poll -> our step is slower -> lead grows.
//  Both keep the snapshot->check->poll64-fallback shape: a stale sample
//  can only cause a poll, never a stale data read.
//  Counted-WAITV budgets re-audited per (wave,layer) incl. a worst-case
//  still-outstanding flag store -- conservative in all cases (FIFO drain).
// Release mechanism unchanged (the only verified one): wave-0 observes
// global flag -> __syncthreads -> all waves load. Publish unchanged:
// pure-store vmcnt(0) drain -> bar(d) -> flag.
// ---------------------------------------------------------------------------
__global__ __launch_bounds__(256, 1) void lstm_mfma(
    const float* __restrict__ b0,
    const float* __restrict__ bb,
    const float* __restrict__ Wout,
    const float* __restrict__ bout,
    float* __restrict__ out,
    const char* __restrict__ WpkB,
    const char* __restrict__ XtB,
    char* __restrict__ RtB,
    int*   __restrict__ seq)
{
    __shared__ floatx4 red[2048];        // [w][mt][nt][lane][4f32] = 32 KB
    // + 56 KB dynamic LDS (unused) forces 1 block/CU

    const int tid  = threadIdx.x;
    const int l    = blockIdx.x >> 6;
    const int wg   = blockIdx.x & 63;
    const int lane = tid & 63;
    const int w    = tid >> 6;
    const int q    = lane >> 4;
    const int r    = lane & 15;
    const int laneoff = q * 512 + r * 16;

    // ---- one-time: B-fragments into registers ----
    half8 bfr[16][4];
    {
        const half8* wb = (const half8*)WpkB + (size_t)(l * 64 + wg) * 16384 + w * 4096 + lane;
        #pragma unroll
        for (int i = 0; i < 16; ++i)
            #pragma unroll
            for (int nt = 0; nt < 4; ++nt)
                bfr[i][nt] = wb[(i * 4 + nt) * 64];
    }
    // l==0: bfr[4..7] are zeros from pack_w and unused (pad tiles skipped)

    // ---- biases + persistent cell state (update threads: tid<128) ----
    float bias4[4] = {0.f, 0.f, 0.f, 0.f};
    float cst[4]   = {0.f, 0.f, 0.f, 0.f};
    const float* biasl = (l == 0) ? b0 : (bb + (size_t)(l - 1) * NG);
    if (tid < 128) {
        #pragma unroll
        for (int g = 0; g < 4; ++g) bias4[g] = biasl[g * 1024 + wg * 16 + (tid & 15)];
    }

    const int* seqm1 = seq + (l - 1) * 64 + lane;   // valid only l>0
    const int* seq0  = seq + l * 64 + lane;
    const int* seqp1 = seq + (l + 1) * 64 + lane;   // valid only l<L-1

    // cond snapshots -- all sampled riding load bursts:
    //   v0 (PB gate)  : wave 0, rides PA burst each step       [R6-proven]
    //   v2 (PA gate)  : wave 0, rides PB burst of prev step    [R7 new]
    //   v3 (ring gate): waves 0-1, rides PA burst each step    [R7 new]
    // v2=0 initial -> t=0 check fails -> poll (correct bootstrap).
    int v0 = 0, v2 = 0, v3 = 0;

    #define ISSUE4(jj, base, LDF) do { \
        const char* p0_ = (base) + (2*(jj)) * 8192; \
        const char* p1_ = (base) + (2*(jj)+1) * 8192; \
        LDF(ab[jj][0], p0_); LDF(ab[jj][1], p0_ + 256); \
        LDF(ab[jj][2], p1_); LDF(ab[jj][3], p1_ + 256); \
    } while (0)

    #define WAITV(N, jj) asm volatile("s_waitcnt vmcnt(" #N ")" \
        : "+v"(ab[jj][0]), "+v"(ab[jj][1]), "+v"(ab[jj][2]), "+v"(ab[jj][3]))

    #define MFMA4(jj, bi) do { \
        _Pragma("unroll") \
        for (int nt = 0; nt < 4; ++nt) { \
            acc[0][nt] = __builtin_amdgcn_mfma_f32_16x16x32_f16(ab[jj][0], bfr[(bi)][nt],   acc[0][nt], 0, 0, 0); \
            acc[1][nt] = __builtin_amdgcn_mfma_f32_16x16x32_f16(ab[jj][1], bfr[(bi)][nt],   acc[1][nt], 0, 0, 0); \
            acc[0][nt] = __builtin_amdgcn_mfma_f32_16x16x32_f16(ab[jj][2], bfr[(bi)+1][nt], acc[0][nt], 0, 0, 0); \
            acc[1][nt] = __builtin_amdgcn_mfma_f32_16x16x32_f16(ab[jj][3], bfr[(bi)+1][nt], acc[1][nt], 0, 0, 0); \
        } \
    } while (0)

    for (int t = 0; t < T; ++t) {
        half8 ab[4][4];
        floatx4 acc[2][4];
        #pragma unroll
        for (int mt = 0; mt < 2; ++mt)
            #pragma unroll
            for (int nt = 0; nt < 4; ++nt) acc[mt][nt] = (floatx4)0.f;

        // ---------- phase A: input half (no own-h dependency) ----------
        if (l == 0) {
            // Xt constant -> plain cached loads; zero-pad k-tiles skipped.
            const char* axb = XtB + (size_t)t * 32768 + w * 2048 + laneoff;
            ISSUE4(0, axb, ld16nc); ISSUE4(1, axb, ld16nc);
            if (tid < 64) ld4cv(v0, seq0);               // PB snapshot ride
            if (l < L - 1 && tid < 128) ld4cv(v3, seqp1);// ring snapshot ride
            // wave0 queue: [flagst?, A0..7, v0, v3]; vmcnt(4) drains >=7 >= 5
            WAITV(4, 0); MFMA4(0, 0);
            WAITV(0, 1); MFMA4(1, 2);
        } else {
            // gate (a): lower layer published h(t). v2 is in-register
            // (sampled riding PB burst of step t-1; drained by its WAITV(0)).
            // vmcnt(1): ordering fence only -- <=1 outstanding (flag store).
            if (tid < 64) {
                asm volatile("s_waitcnt vmcnt(1)" : "+v"(v2));
                if (!__all(v2 >= t + 1)) poll64(seqm1, t + 1);
            }
            __syncthreads();   // verified release: observe -> barrier -> load
            const char* axb = RtB + (size_t)((l - 1) * 8 + slot(t)) * 65536 + w * 2048 + laneoff;
            ISSUE4(0, axb, ld16); ISSUE4(1, axb, ld16);
            ISSUE4(2, axb, ld16); ISSUE4(3, axb, ld16);
            if (tid < 64) ld4cv(v0, seq0);               // PB snapshot ride
            if (l < L - 1 && tid < 128) ld4cv(v3, seqp1);// ring snapshot ride
            // wave0 queue: [flagst?, A0..15, v0, v3]:
            //   12 -> drains >=6 >= 5 (flagst+A0-3); 8 -> >=10 >= 9;
            //   4 -> >=14 >= 13; 0 -> all (v0, v3 in regs).
            WAITV(12, 0); MFMA4(0, 0);
            WAITV(8, 1);  MFMA4(1, 2);
            WAITV(4, 2);  MFMA4(2, 4);
            WAITV(0, 3);  MFMA4(3, 6);
        }

        // ---------- gate (b): own layer h(t-1) from all 64 wgs ----------
        if (tid < 64) {
            // v0 drained by phase A's WAITV(0); outstanding = 0 -> free.
            asm volatile("s_waitcnt vmcnt(0)" : "+v"(v0));
            if (!__all(v0 >= t)) poll64(seq0, t);
        }
        __syncthreads();   // verified release
        {
            const char* ahb = RtB + (size_t)(l * 8 + slot(t - 1)) * 65536 + w * 2048 + laneoff;
            ISSUE4(0, ahb, ld16); ISSUE4(1, ahb, ld16);
            ISSUE4(2, ahb, ld16); ISSUE4(3, ahb, ld16);
            if (tid < 64 && l > 0) ld4cv(v2, seqm1);     // PA snapshot ride (next step)
            // wave0 queue: [B0..15, v2]: 12 -> 5 >= 4; 8 -> 9 >= 8;
            //   4 -> 13 >= 12; 0 -> all (v2 in reg for next step's gate a).
            WAITV(12, 0); MFMA4(0, 8);
            WAITV(8, 1);  MFMA4(1, 10);
            WAITV(4, 2);  MFMA4(2, 12);
            WAITV(0, 3);  MFMA4(3, 14);
        }

        // ---- cross-wave reduce via LDS ----
        #pragma unroll
        for (int mt = 0; mt < 2; ++mt)
            #pragma unroll
            for (int nt = 0; nt < 4; ++nt)
                red[((w * 2 + mt) * 4 + nt) * 64 + lane] = acc[mt][nt];
        __syncthreads();   // (c)

        // ---- gate sums + cell update + DIRECT h publish (threads 0..127) ----
        if (tid < 128) {
            if (l < L - 1) {
                // ring gate: slot(t) still holds h(t-8); layer l+1 must be
                // past phase A of step t-8, i.e. seq_{l+1} >= t-RING+1.
                // v3 drained by PA/PB WAITV(0) -> this vmcnt(0) is free.
                asm volatile("s_waitcnt vmcnt(0)" : "+v"(v3));
                if (t >= RING && !__all(v3 >= t - RING + 1)) poll64(seqp1, t - RING + 1);
            }
            const int u = tid & 15, mq = (tid >> 4) & 7, mt = mq >> 2, qq = mq & 3;
            const int lp = qq * 16 + u;
            floatx4 s0 = (floatx4)0.f, s1 = (floatx4)0.f, s2 = (floatx4)0.f, s3 = (floatx4)0.f;
            #pragma unroll
            for (int w2 = 0; w2 < 4; ++w2) {
                s0 += red[((w2 * 2 + mt) * 4 + 0) * 64 + lp];
                s1 += red[((w2 * 2 + mt) * 4 + 1) * 64 + lp];
                s2 += red[((w2 * 2 + mt) * 4 + 2) * 64 + lp];
                s3 += red[((w2 * 2 + mt) * 4 + 3) * 64 + lp];
            }
            // h[m][u] -> ring byte: K=wg>>1 (*2048), Q=(wg&1)*2+(u>>3) (*512),
            // m*16, (u&7)*2  (identical to R1/R3/R6's layout)
            char* hp = RtB + (size_t)(l * 8 + slot(t)) * 65536
                     + (size_t)(wg >> 1) * 2048 + ((wg & 1) * 2 + (u >> 3)) * 512
                     + (u & 7) * 2;
            #pragma unroll
            for (int rr = 0; rr < 4; ++rr) {
                float gi = s0[rr] + bias4[0];
                float gf = s1[rr] + bias4[1];
                float gg = s2[rr] + bias4[2];
                float go = s3[rr] + bias4[3];
                float cn = sigf(gf) * cst[rr] + sigf(gi) * tanhfast(gg);
                cst[rr] = cn;
                float hv = sigf(go) * tanhfast(cn);
                int m = mt * 16 + qq * 4 + rr;
                union { _Float16 h; unsigned short s; } cvh; cvh.h = (_Float16)hv;
                st2(hp + m * 16, (int)cvh.s);
            }
            // pure-store full drain (verified ordering primitive):
            // this wave's h stores are acked at the coherence point.
            asm volatile("s_waitcnt vmcnt(0)");
        }
        __syncthreads();   // (d) both update waves drained before the flag

        // ---- publish flag (wave 0, fire-and-forget) ----
        if (tid == 0) st4cv(seq + l * 64 + wg, t + 1);
    }

    #undef ISSUE4
    #undef WAITV
    #undef MFMA4

    // ---- output projection (layer-0 blocks) ----
    if (l != 0) return;
    if (tid < 64) poll64(seq + (L - 1) * 64 + lane, T);
    __syncthreads();

    const int b  = blockIdx.x >> 1;
    const int o0 = (blockIdx.x & 1) << 8;
    const char* rt3 = RtB + (size_t)((L - 1) * 8 + slot(T - 1)) * 65536;
    float* hb = (float*)red;
    if (tid < 128) {
        int j0 = tid * 8;
        half8 hv;
        ld16(hv, rt3 + ((j0 >> 5) * 2048 + ((j0 >> 3) & 3) * 512 + b * 16));
        asm volatile("s_waitcnt vmcnt(0)" : "+v"(hv));
        #pragma unroll
        for (int k2 = 0; k2 < 8; ++k2) hb[j0 + k2] = (float)hv[k2];
    }
    __syncthreads();
    const int o = o0 + tid;
    float s = bout[o];
    #pragma unroll 8
    for (int j = 0; j < H; ++j)
        s += hb[j] * Wout[(size_t)j * D_OUT + o];
    out[(size_t)b * D_OUT + o] = s;
}

extern "C" void kernel_launch(void* const* d_in, const int* in_sizes, int n_in,
                              void* d_out, int out_size, void* d_ws, size_t ws_size,
                              hipStream_t stream) {
    const float* x    = (const float*)d_in[0];
    const float* Wx0  = (const float*)d_in[1];
    const float* Wh0  = (const float*)d_in[2];
    const float* b0   = (const float*)d_in[3];
    const float* Wx   = (const float*)d_in[4];
    const float* Wh   = (const float*)d_in[5];
    const float* bb   = (const float*)d_in[6];
    const float* Wout = (const float*)d_in[7];
    const float* bout = (const float*)d_in[8];
    float* out = (float*)d_out;

    char* ws = (char*)d_ws;
    uint32_t* Wpk  = (uint32_t*)(ws + OFF_WPK);
    uint32_t* Xt   = (uint32_t*)(ws + OFF_XT);
    char*     Rt   = ws + OFF_RT;
    int*      seq  = (int*)(ws + OFF_FLG);

    hipMemsetAsync(Rt, 0, 2097152, stream);              // h(-1) = 0
    hipMemsetAsync(seq, 0, L * 64 * sizeof(int), stream);

    pack_w<<<dim3(65536), dim3(256), 0, stream>>>(Wx0, Wh0, Wx, Wh, Wpk);
    tile_x<<<dim3(16384), dim3(256), 0, stream>>>(x, Xt);

    hipFuncSetAttribute(reinterpret_cast<const void*>(&lstm_mfma),
                        hipFuncAttributeMaxDynamicSharedMemorySize, 57344);
    lstm_mfma<<<dim3(256), dim3(256), 57344, stream>>>(
        b0, bb, Wout, bout, out, (const char*)Wpk, (const char*)Xt, Rt, seq);
}